// Round 4
// baseline (13.194 us; speedup 1.0000x reference)
//
#include <hip/hip_runtime.h>

#define N_QUERIES 2097152

// Block = 256 threads, 2048 queries. Thread issues 4 unit-stride float4 loads
// back-to-back (4-deep MLP), computes 8 queries, stages 24 KB in LDS, then
// 6 unit-stride float4 stores. Half the barrier generations of round 3.
__device__ __forceinline__ float4 nearest_col(float qx, float qy,
                                              const float4* __restrict__ pairs,
                                              const float4* __restrict__ cols)
{
    // nearest 2x2 cell-center block; jitter margin (0.1179 vs 0.0955) proves
    // the global argmin over all 64 jittered sites lies in this block.
    float fx = qx * 8.0f - 0.5f;
    float fy = qy * 8.0f - 0.5f;
    float fi = fminf(fmaxf(floorf(fx), 0.0f), 6.0f);
    float fj = fminf(fmaxf(floorf(fy), 0.0f), 6.0f);
    int k0 = (int)fi * 8 + (int)fj;

    float4 r0 = pairs[k0];       // sites k0, k0+1
    float4 r1 = pairs[k0 + 8];   // sites k0+8, k0+9

    // ascending k + strict '<' == np.argmin tie-break;
    // __fmul_rn/__fadd_rn match numpy's separate roundings (no FMA).
    float dx, dy, d2, best;
    int bk = k0;
    dx = qx - r0.x; dy = qy - r0.y;
    best = __fadd_rn(__fmul_rn(dx, dx), __fmul_rn(dy, dy));
    dx = qx - r0.z; dy = qy - r0.w;
    d2 = __fadd_rn(__fmul_rn(dx, dx), __fmul_rn(dy, dy));
    if (d2 < best) { best = d2; bk = k0 + 1; }
    dx = qx - r1.x; dy = qy - r1.y;
    d2 = __fadd_rn(__fmul_rn(dx, dx), __fmul_rn(dy, dy));
    if (d2 < best) { best = d2; bk = k0 + 8; }
    dx = qx - r1.z; dy = qy - r1.w;
    d2 = __fadd_rn(__fmul_rn(dx, dx), __fmul_rn(dy, dy));
    if (d2 < best) { best = d2; bk = k0 + 9; }

    return cols[bk];
}

__global__ __launch_bounds__(256) void voronoi_kernel(
    const float* __restrict__ x,
    const float* __restrict__ p,
    float* __restrict__ out)
{
    __shared__ float4 pairs[64];
    __shared__ float4 cols[64];
    __shared__ float  oc[6144];   // 24 KB output staging (2048 queries x 3)

    const int tid = threadIdx.x;
    if (tid < 64) {
        int nb = ((tid & 7) == 7) ? tid : tid + 1;
        pairs[tid] = make_float4(p[tid * 5 + 0], p[tid * 5 + 1],
                                 p[nb * 5 + 0],  p[nb * 5 + 1]);
        cols[tid]  = make_float4(p[tid * 5 + 2], p[tid * 5 + 3],
                                 p[tid * 5 + 4], 0.0f);
    }
    __syncthreads();

    // 4 unit-stride float4 loads issued back-to-back (4-deep MLP)
    const float4* __restrict__ x4 = (const float4*)x + (size_t)blockIdx.x * 1024;
    float4 v[4];
    #pragma unroll
    for (int g = 0; g < 4; ++g) v[g] = x4[tid + 256 * g];

    // compute 8 queries, stage into LDS (24B-stride pairs: 4-way aliasing only)
    #pragma unroll
    for (int g = 0; g < 4; ++g) {
        float4 c0 = nearest_col(v[g].x, v[g].y, pairs, cols);
        float4 c1 = nearest_col(v[g].z, v[g].w, pairs, cols);
        float* o = &oc[1536 * g + 6 * tid];
        o[0] = c0.x; o[1] = c0.y; o[2] = c0.z;
        o[3] = c1.x; o[4] = c1.y; o[5] = c1.z;
    }
    __syncthreads();

    // 6 unit-stride float4 stores
    float4* __restrict__ o4 = (float4*)out + (size_t)blockIdx.x * 1536;
    const float4* __restrict__ ocv = (const float4*)oc;
    #pragma unroll
    for (int g = 0; g < 6; ++g) o4[tid + 256 * g] = ocv[tid + 256 * g];
}

extern "C" void kernel_launch(void* const* d_in, const int* in_sizes, int n_in,
                              void* d_out, int out_size, void* d_ws, size_t ws_size,
                              hipStream_t stream) {
    const float* x = (const float*)d_in[0];
    const float* p = (const float*)d_in[1];
    float* out = (float*)d_out;

    const int block = 256;
    const int grid = N_QUERIES / 2048;   // 1024 blocks -> 4/CU, 16 waves/CU
    voronoi_kernel<<<grid, block, 0, stream>>>(x, p, out);
}

// Round 6
// 10.852 us; speedup vs baseline: 1.2158x; 1.2158x over previous
//
#include <hip/hip_runtime.h>

#define N_QUERIES 2097152

typedef float fx4 __attribute__((ext_vector_type(4)));  // native vec for nontemporal builtin

// Block = 256 threads, 1024 queries (R3 structure: best so far).
// Site table in LDS as SoA b32 (px|py|r|g|b at 64-float strides) so every
// gather is ds_read_b32 -> conflict classes span all 32 banks (~2-way = free),
// vs R3's b128 gathers (classes = k mod 8, ~8-way).
__device__ __forceinline__ float4 nearest_col(float qx, float qy,
                                              const float* __restrict__ sp)
{
    // nearest 2x2 cell-center block; jitter margin (0.1179 vs 0.0955) proves
    // the global argmin over all 64 jittered sites lies in this block.
    float fx = qx * 8.0f - 0.5f;
    float fy = qy * 8.0f - 0.5f;
    float fi = fminf(fmaxf(floorf(fx), 0.0f), 6.0f);
    float fj = fminf(fmaxf(floorf(fy), 0.0f), 6.0f);
    int k0 = (int)fi * 8 + (int)fj;

    const float* base = sp + k0;
    // candidates k0, k0+1, k0+8, k0+9 — ascending k + strict '<' matches
    // np.argmin tie-break; __fmul_rn/__fadd_rn match numpy (no FMA).
    float pxa = base[0],  pxb = base[1],  pxc = base[8],  pxd = base[9];
    float pya = base[64], pyb = base[65], pyc = base[72], pyd = base[73];

    float dx, dy, d2, best;
    int bk = k0;
    dx = qx - pxa; dy = qy - pya;
    best = __fadd_rn(__fmul_rn(dx, dx), __fmul_rn(dy, dy));
    dx = qx - pxb; dy = qy - pyb;
    d2 = __fadd_rn(__fmul_rn(dx, dx), __fmul_rn(dy, dy));
    if (d2 < best) { best = d2; bk = k0 + 1; }
    dx = qx - pxc; dy = qy - pyc;
    d2 = __fadd_rn(__fmul_rn(dx, dx), __fmul_rn(dy, dy));
    if (d2 < best) { best = d2; bk = k0 + 8; }
    dx = qx - pxd; dy = qy - pyd;
    d2 = __fadd_rn(__fmul_rn(dx, dx), __fmul_rn(dy, dy));
    if (d2 < best) { best = d2; bk = k0 + 9; }

    return make_float4(sp[128 + bk], sp[192 + bk], sp[256 + bk], 0.0f);
}

__global__ __launch_bounds__(256) void voronoi_kernel(
    const float* __restrict__ x,
    const float* __restrict__ p,
    float* __restrict__ out)
{
    __shared__ float sp[320];    // px[64] py[64] r[64] g[64] b[64]
    __shared__ float oc[3072];   // 12 KB output staging (1024 queries x 3)

    const int tid = threadIdx.x;
    if (tid < 64) {
        sp[tid]       = p[tid * 5 + 0];
        sp[64 + tid]  = p[tid * 5 + 1];
        sp[128 + tid] = p[tid * 5 + 2];
        sp[192 + tid] = p[tid * 5 + 3];
        sp[256 + tid] = p[tid * 5 + 4];
    }
    __syncthreads();

    // coalesced loads: lane-consecutive float4
    const float4* __restrict__ x4 = (const float4*)x + (size_t)blockIdx.x * 512;
    float4 a = x4[tid];         // queries 2t, 2t+1 (block-relative)
    float4 b = x4[256 + tid];   // queries 512+2t, 512+2t+1

    float4 c0 = nearest_col(a.x, a.y, sp);
    float4 c1 = nearest_col(a.z, a.w, sp);
    float4 c2 = nearest_col(b.x, b.y, sp);
    float4 c3 = nearest_col(b.z, b.w, sp);

    // stage output tile in LDS
    float* o0 = &oc[6 * tid];
    o0[0] = c0.x; o0[1] = c0.y; o0[2] = c0.z;
    o0[3] = c1.x; o0[4] = c1.y; o0[5] = c1.z;
    float* o1 = &oc[1536 + 6 * tid];
    o1[0] = c2.x; o1[1] = c2.y; o1[2] = c2.z;
    o1[3] = c3.x; o1[4] = c3.y; o1[5] = c3.z;
    __syncthreads();

    // coalesced nontemporal stores: lane-consecutive 16B via native vec type
    fx4* __restrict__ o4 = (fx4*)out + (size_t)blockIdx.x * 768;
    const fx4* __restrict__ ocv = (const fx4*)oc;
    __builtin_nontemporal_store(ocv[tid],       &o4[tid]);
    __builtin_nontemporal_store(ocv[256 + tid], &o4[256 + tid]);
    __builtin_nontemporal_store(ocv[512 + tid], &o4[512 + tid]);
}

extern "C" void kernel_launch(void* const* d_in, const int* in_sizes, int n_in,
                              void* d_out, int out_size, void* d_ws, size_t ws_size,
                              hipStream_t stream) {
    const float* x = (const float*)d_in[0];
    const float* p = (const float*)d_in[1];
    float* out = (float*)d_out;

    const int block = 256;
    const int grid = N_QUERIES / 1024;   // 2048 blocks -> 8/CU, 32 waves/CU
    voronoi_kernel<<<grid, block, 0, stream>>>(x, p, out);
}